// Round 2
// baseline (1303.056 us; speedup 1.0000x reference)
//
#include <hip/hip_runtime.h>
#include <hip/hip_bf16.h>

typedef unsigned short ushort_t;
typedef unsigned int uint_t;

#define DI __device__ __forceinline__

// bf16 bits -> f32
DI float b2f(uint_t lo16) {
    union { uint_t u; float f; } v; v.u = lo16 << 16; return v.f;
}
// f32 -> bf16 bits, round-to-nearest-even
DI ushort_t f2b(float f) {
    union { float f; uint_t u; } v; v.f = f;
    uint_t u = v.u;
    uint_t r = (u + 0x7fffu + ((u >> 16) & 1u)) >> 16;
    return (ushort_t)r;
}

// ---------------- degree + histogram ----------------
__global__ __launch_bounds__(256) void gcn_deg_hist(
    const int* __restrict__ ei, const float* __restrict__ ew,
    float* __restrict__ deg, int* __restrict__ cnt, int E)
{
    int e = blockIdx.x * 256 + threadIdx.x;
    if (e >= E) return;
    int d = ei[E + e];
    float w = fabsf(ew[e]);
    atomicAdd(&deg[d], w);
    atomicAdd(&cnt[d], 1);
}

// deg -> dis = rsqrt(deg+1), in place
__global__ __launch_bounds__(256) void gcn_dis(float* __restrict__ deg, int N)
{
    int i = blockIdx.x * 256 + threadIdx.x;
    if (i >= N) return;
    deg[i] = rsqrtf(deg[i] + 1.0f);
}

// ---------------- exclusive scan (3 kernels, 1024 elems/block) ----------------
__global__ __launch_bounds__(256) void gcn_scan1(
    const int* __restrict__ cnt, int* __restrict__ rp, int* __restrict__ bsum, int N)
{
    __shared__ int lds[256];
    int t = threadIdx.x;
    int base = blockIdx.x * 1024 + t * 4;
    int v0 = (base + 0 < N) ? cnt[base + 0] : 0;
    int v1 = (base + 1 < N) ? cnt[base + 1] : 0;
    int v2 = (base + 2 < N) ? cnt[base + 2] : 0;
    int v3 = (base + 3 < N) ? cnt[base + 3] : 0;
    int s = v0 + v1 + v2 + v3;
    lds[t] = s;
    __syncthreads();
    #pragma unroll
    for (int off = 1; off < 256; off <<= 1) {
        int y = (t >= off) ? lds[t - off] : 0;
        __syncthreads();
        lds[t] += y;
        __syncthreads();
    }
    int incl = lds[t];
    int excl = incl - s;
    if (base + 0 < N) rp[base + 0] = excl;
    if (base + 1 < N) rp[base + 1] = excl + v0;
    if (base + 2 < N) rp[base + 2] = excl + v0 + v1;
    if (base + 3 < N) rp[base + 3] = excl + v0 + v1 + v2;
    if (t == 255) bsum[blockIdx.x] = incl;
}

__global__ __launch_bounds__(256) void gcn_scan2(
    int* __restrict__ bsum, int* __restrict__ rp, int nb, int N, int E)
{
    __shared__ int lds[256];
    int t = threadIdx.x;
    int s = (t < nb) ? bsum[t] : 0;
    lds[t] = s;
    __syncthreads();
    #pragma unroll
    for (int off = 1; off < 256; off <<= 1) {
        int y = (t >= off) ? lds[t - off] : 0;
        __syncthreads();
        lds[t] += y;
        __syncthreads();
    }
    int incl = lds[t];
    if (t < nb) bsum[t] = incl - s;
    if (t == 0) rp[N] = E;
}

__global__ __launch_bounds__(256) void gcn_scan3(
    int* __restrict__ rp, int* __restrict__ cursor, const int* __restrict__ bsum, int N)
{
    int i = blockIdx.x * 256 + threadIdx.x;
    if (i >= N) return;
    int v = rp[i] + bsum[i >> 10];
    rp[i] = v;
    cursor[i] = v;
}

// ---------------- CSR fill: (src, norm) sorted by dst ----------------
__global__ __launch_bounds__(256) void gcn_fill(
    const int* __restrict__ ei, const float* __restrict__ ew,
    const float* __restrict__ dis, int* __restrict__ cursor,
    int* __restrict__ rsrc, float* __restrict__ rnrm, int E)
{
    int e = blockIdx.x * 256 + threadIdx.x;
    if (e >= E) return;
    int s = ei[e];
    int d = ei[E + e];
    float w = fabsf(ew[e]);
    float nrm = dis[s] * w * dis[d];
    int pos = atomicAdd(&cursor[d], 1);
    rsrc[pos] = s;
    rnrm[pos] = nrm;
}

// ---------------- GEMM (fp32 X): Y[n,:FOUTP](bf16) = X[n,:FIN] @ W ----------------
template<int FIN, int FOUT, int FOUTP>
__global__ __launch_bounds__(256) void gcn_gemm_f32(
    const float* __restrict__ X, const float* __restrict__ W,
    ushort_t* __restrict__ Y, int N)
{
    int n = blockIdx.x * 256 + threadIdx.x;
    if (n >= N) return;
    const float4* xrow = (const float4*)(X + (size_t)n * FIN);
    float acc[FOUT];
    #pragma unroll
    for (int f = 0; f < FOUT; f++) acc[f] = 0.0f;

    for (int kb = 0; kb < FIN / 4; kb++) {
        float4 xv = xrow[kb];
        const float* xk4 = (const float*)&xv;
        #pragma unroll
        for (int kk = 0; kk < 4; kk++) {
            float xk = xk4[kk];
            const float* wr = W + (size_t)(kb * 4 + kk) * FOUT;
            #pragma unroll
            for (int f = 0; f < FOUT; f++) acc[f] += xk * wr[f];
        }
    }

    uint_t* y = (uint_t*)(Y + (size_t)n * FOUTP);
    #pragma unroll
    for (int fp = 0; fp < FOUT / 2; fp++) {
        uint_t v = (uint_t)f2b(acc[2 * fp]) | ((uint_t)f2b(acc[2 * fp + 1]) << 16);
        y[fp] = v;
    }
    #pragma unroll
    for (int fp = FOUT / 2; fp < FOUTP / 2; fp++) y[fp] = 0;
}

// ---------------- GEMM (bf16 X): Y[n,:FOUTP](bf16) = X[n,:FIN] @ W(fp32) ----------------
template<int FIN, int FOUT, int FOUTP>
__global__ __launch_bounds__(256) void gcn_gemm_b16(
    const ushort_t* __restrict__ X, const float* __restrict__ W,
    ushort_t* __restrict__ Y, int N)
{
    int n = blockIdx.x * 256 + threadIdx.x;
    if (n >= N) return;
    const uint4* xrow = (const uint4*)(X + (size_t)n * FIN);
    float acc[FOUT];
    #pragma unroll
    for (int f = 0; f < FOUT; f++) acc[f] = 0.0f;

    for (int kb = 0; kb < FIN / 8; kb++) {
        uint4 xv = xrow[kb];
        const uint_t* xw32 = (const uint_t*)&xv;
        #pragma unroll
        for (int kk = 0; kk < 8; kk++) {
            uint_t xpair = xw32[kk >> 1];
            float xk = b2f((kk & 1) ? (xpair >> 16) : (xpair & 0xffffu));
            const float* wr = W + (size_t)(kb * 8 + kk) * FOUT;
            #pragma unroll
            for (int f = 0; f < FOUT; f++) acc[f] += xk * wr[f];
        }
    }

    uint_t* y = (uint_t*)(Y + (size_t)n * FOUTP);
    #pragma unroll
    for (int fp = 0; fp < FOUT / 2; fp++) {
        uint_t v = (uint_t)f2b(acc[2 * fp]) | ((uint_t)f2b(acc[2 * fp + 1]) << 16);
        y[fp] = v;
    }
    #pragma unroll
    for (int fp = FOUT / 2; fp < FOUTP / 2; fp++) y[fp] = 0;
}

// ---------------- aggregation: H[n] = relu(b + dis[n]^2*XW[n] + sum_e nrm*XW[src]) ----
// LPN lanes per node, each lane owns a 4-bf16 chunk of the feature row
template<int FOUT, int FOUTP, int LPN, int BLK>
__global__ __launch_bounds__(BLK) void gcn_agg(
    const ushort_t* __restrict__ XW, const int* __restrict__ rp,
    const int* __restrict__ rsrc, const float* __restrict__ rnrm,
    const float* __restrict__ dis, const float* __restrict__ bias,
    ushort_t* __restrict__ H, int N)
{
    constexpr int NC = FOUTP / 4;
    int n = blockIdx.x * (BLK / LPN) + threadIdx.x / LPN;
    int c = threadIdx.x % LPN;
    if (n >= N) return;
    const uint2* xwc = (const uint2*)XW;

    int beg = rp[n], end = rp[n + 1];
    float a0 = 0.f, a1 = 0.f, a2 = 0.f, a3 = 0.f;
    for (int e = beg; e < end; e++) {
        int s = rsrc[e];
        float nm = rnrm[e];
        uint2 v = xwc[(size_t)s * NC + c];
        a0 += nm * b2f(v.x & 0xffffu);
        a1 += nm * b2f(v.x >> 16);
        a2 += nm * b2f(v.y & 0xffffu);
        a3 += nm * b2f(v.y >> 16);
    }
    float d = dis[n];
    float sn = d * d;
    uint2 sv = xwc[(size_t)n * NC + c];
    a0 += sn * b2f(sv.x & 0xffffu);
    a1 += sn * b2f(sv.x >> 16);
    a2 += sn * b2f(sv.y & 0xffffu);
    a3 += sn * b2f(sv.y >> 16);

    int f0 = c * 4;
    float r0 = (f0 + 0 < FOUT) ? fmaxf(a0 + bias[f0 + 0], 0.f) : 0.f;
    float r1 = (f0 + 1 < FOUT) ? fmaxf(a1 + bias[f0 + 1], 0.f) : 0.f;
    float r2 = (f0 + 2 < FOUT) ? fmaxf(a2 + bias[f0 + 2], 0.f) : 0.f;
    float r3 = (f0 + 3 < FOUT) ? fmaxf(a3 + bias[f0 + 3], 0.f) : 0.f;

    uint2 o;
    o.x = (uint_t)f2b(r0) | ((uint_t)f2b(r1) << 16);
    o.y = (uint_t)f2b(r2) | ((uint_t)f2b(r3) << 16);
    ((uint2*)H)[(size_t)n * NC + c] = o;
}

// ---------------- mean-pool per graph + final linear + softmax ----------------
__global__ __launch_bounds__(256) void gcn_pool(
    const ushort_t* __restrict__ H, const int* __restrict__ batch,
    const float* __restrict__ Wf, const float* __restrict__ bf_,
    float* __restrict__ out, int N)
{
    __shared__ float pool[32];
    int g = blockIdx.x;
    int t = threadIdx.x;

    // lower_bound over sorted batch
    int lo = 0, hi = N;
    while (lo < hi) { int mid = (lo + hi) >> 1; if (batch[mid] < g) lo = mid + 1; else hi = mid; }
    int start = lo;
    lo = 0; hi = N;
    while (lo < hi) { int mid = (lo + hi) >> 1; if (batch[mid] < g + 1) lo = mid + 1; else hi = mid; }
    int end = lo;

    float acc[32];
    #pragma unroll
    for (int f = 0; f < 32; f++) acc[f] = 0.0f;
    for (int i = start + t; i < end; i += 256) {
        const uint2* hr = (const uint2*)H + (size_t)i * 8;
        #pragma unroll
        for (int q = 0; q < 8; q++) {
            uint2 v = hr[q];
            acc[4 * q + 0] += b2f(v.x & 0xffffu);
            acc[4 * q + 1] += b2f(v.x >> 16);
            acc[4 * q + 2] += b2f(v.y & 0xffffu);
            acc[4 * q + 3] += b2f(v.y >> 16);
        }
    }
    #pragma unroll
    for (int f = 0; f < 32; f++) {
        float v = acc[f];
        v += __shfl_down(v, 32, 64);
        v += __shfl_down(v, 16, 64);
        v += __shfl_down(v, 8, 64);
        v += __shfl_down(v, 4, 64);
        v += __shfl_down(v, 2, 64);
        v += __shfl_down(v, 1, 64);
        acc[f] = v;
    }
    if (t < 32) pool[t] = 0.0f;
    __syncthreads();
    if ((t & 63) == 0) {
        #pragma unroll
        for (int f = 0; f < 30; f++) atomicAdd(&pool[f], acc[f]);
    }
    __syncthreads();
    if (t == 0) {
        float inv = 1.0f / fmaxf((float)(end - start), 1.0f);
        float lg[10];
        #pragma unroll
        for (int j = 0; j < 10; j++) lg[j] = bf_[j];
        for (int f = 0; f < 30; f++) {
            float p = pool[f] * inv;
            #pragma unroll
            for (int j = 0; j < 10; j++) lg[j] += p * Wf[f * 10 + j];
        }
        float m = lg[0];
        #pragma unroll
        for (int j = 1; j < 10; j++) m = fmaxf(m, lg[j]);
        float s = 0.f;
        #pragma unroll
        for (int j = 0; j < 10; j++) { lg[j] = __expf(lg[j] - m); s += lg[j]; }
        float is = 1.0f / s;
        #pragma unroll
        for (int j = 0; j < 10; j++) out[g * 10 + j] = lg[j] * is;
    }
}

extern "C" void kernel_launch(void* const* d_in, const int* in_sizes, int n_in,
                              void* d_out, int out_size, void* d_ws, size_t ws_size,
                              hipStream_t stream) {
    (void)n_in; (void)out_size; (void)ws_size;
    const float* x   = (const float*)d_in[0];
    const int*   ei  = (const int*)d_in[1];
    const float* ew  = (const float*)d_in[2];
    const int*   bat = (const int*)d_in[3];
    const float* W1  = (const float*)d_in[4];
    const float* b1  = (const float*)d_in[5];
    const float* W2  = (const float*)d_in[6];
    const float* b2  = (const float*)d_in[7];
    const float* W3  = (const float*)d_in[8];
    const float* b3  = (const float*)d_in[9];
    const float* Wf  = (const float*)d_in[10];
    const float* bf_ = (const float*)d_in[11];
    float* out = (float*)d_out;

    const int N = in_sizes[3];       // 100000
    const int E = in_sizes[2];       // 3200000
    const size_t N4 = (size_t)N * 4;

    char* wsb = (char*)d_ws;
    size_t o = 0;
    float* deg = (float*)(wsb);          // N floats (becomes dis after gcn_dis)
    int*   cnt = (int*)(wsb + N4);       // N ints  (contiguous with deg -> one memset)
    o = (2 * N4 + 255) & ~(size_t)255;
    auto take = [&](size_t bytes) -> char* {
        char* p = wsb + o;
        o += (bytes + 255) & ~(size_t)255;
        return p;
    };
    int*      rp     = (int*)take((size_t)(N + 1) * 4);
    int*      cursor = (int*)take(N4);
    int*      bsum   = (int*)take(4096);
    int*      rsrc   = (int*)take((size_t)E * 4);
    float*    rnrm   = (float*)take((size_t)E * 4);
    ushort_t* xw     = (ushort_t*)take((size_t)N * 96 * 2);
    ushort_t* h      = (ushort_t*)take((size_t)N * 96 * 2);

    const int gE = (E + 255) / 256;
    const int gN = (N + 255) / 256;
    const int nb = (N + 1023) / 1024;

    // zero deg + cnt
    hipMemsetAsync(wsb, 0, 2 * N4, stream);

    // normalization precompute + CSR build
    gcn_deg_hist<<<gE, 256, 0, stream>>>(ei, ew, deg, cnt, E);
    gcn_dis<<<gN, 256, 0, stream>>>(deg, N);
    gcn_scan1<<<nb, 256, 0, stream>>>(cnt, rp, bsum, N);
    gcn_scan2<<<1, 256, 0, stream>>>(bsum, rp, nb, N, E);
    gcn_scan3<<<gN, 256, 0, stream>>>(rp, cursor, bsum, N);
    gcn_fill<<<gE, 256, 0, stream>>>(ei, ew, deg, cursor, rsrc, rnrm, E);

    // layer 1: x[.,128](fp32) -> xw[.,96](bf16) -> h[.,96](bf16)
    gcn_gemm_f32<128, 96, 96><<<gN, 256, 0, stream>>>(x, W1, xw, N);
    gcn_agg<96, 96, 24, 192><<<(N + 7) / 8, 192, 0, stream>>>(xw, rp, rsrc, rnrm, deg, b1, h, N);

    // layer 2: h[.,96] -> xw[.,96] -> h[.,96]
    gcn_gemm_b16<96, 96, 96><<<gN, 256, 0, stream>>>(h, W2, xw, N);
    gcn_agg<96, 96, 24, 192><<<(N + 7) / 8, 192, 0, stream>>>(xw, rp, rsrc, rnrm, deg, b2, h, N);

    // layer 3: h[.,96] -> xw[.,32 (30 used)] -> h[.,32]
    gcn_gemm_b16<96, 30, 32><<<gN, 256, 0, stream>>>(h, W3, xw, N);
    gcn_agg<30, 32, 8, 256><<<(N + 31) / 32, 256, 0, stream>>>(xw, rp, rsrc, rnrm, deg, b3, h, N);

    // mean pool + classifier + softmax
    gcn_pool<<<256, 256, 0, stream>>>(h, bat, Wf, bf_, out, N);
}

// Round 3
// 1094.400 us; speedup vs baseline: 1.1907x; 1.1907x over previous
//
#include <hip/hip_runtime.h>
#include <hip/hip_bf16.h>

typedef unsigned short ushort_t;
typedef unsigned int uint_t;
typedef unsigned long long u64_t;

#define DI __device__ __forceinline__

// bf16 bits -> f32
DI float b2f(uint_t lo16) {
    union { uint_t u; float f; } v; v.u = lo16 << 16; return v.f;
}
// f32 -> bf16 bits, round-to-nearest-even
DI ushort_t f2b(float f) {
    union { float f; uint_t u; } v; v.f = f;
    uint_t u = v.u;
    uint_t r = (u + 0x7fffu + ((u >> 16) & 1u)) >> 16;
    return (ushort_t)r;
}

// ---------------- fused degree+count histogram: one u64 atomic per edge ------
// dh[d] += (1<<40) | round(|w| * 2^23)
// count field: bits [40,64); weight-sum field: bits [0,40) in 2^-23 fixed point.
// max degree ~O(100) -> sum < 2^31, count < 2^24: no field overflow.
__global__ __launch_bounds__(256) void gcn_deg_hist(
    const int* __restrict__ ei, const float* __restrict__ ew,
    u64_t* __restrict__ dh, int E)
{
    int e = blockIdx.x * 256 + threadIdx.x;
    if (e >= E) return;
    int d = ei[E + e];
    float w = fabsf(ew[e]);
    u64_t v = (1ULL << 40) | (u64_t)__float2uint_rn(w * 8388608.0f);
    atomicAdd(&dh[d], v);
}

// dh -> dis = rsqrt(deg+1), cnt
__global__ __launch_bounds__(256) void gcn_dis(
    const u64_t* __restrict__ dh, float* __restrict__ dis,
    int* __restrict__ cnt, int N)
{
    int i = blockIdx.x * 256 + threadIdx.x;
    if (i >= N) return;
    u64_t v = dh[i];
    cnt[i] = (int)(v >> 40);
    // weight-sum < 2^32 (max degree-sum ~100 << 512), safe to truncate to u32
    float deg = (float)(uint_t)(v & 0xFFFFFFFFFFULL) * (1.0f / 8388608.0f);
    dis[i] = rsqrtf(deg + 1.0f);
}

// ---------------- exclusive scan (3 kernels, 1024 elems/block) ----------------
__global__ __launch_bounds__(256) void gcn_scan1(
    const int* __restrict__ cnt, int* __restrict__ rp, int* __restrict__ bsum, int N)
{
    __shared__ int lds[256];
    int t = threadIdx.x;
    int base = blockIdx.x * 1024 + t * 4;
    int v0 = (base + 0 < N) ? cnt[base + 0] : 0;
    int v1 = (base + 1 < N) ? cnt[base + 1] : 0;
    int v2 = (base + 2 < N) ? cnt[base + 2] : 0;
    int v3 = (base + 3 < N) ? cnt[base + 3] : 0;
    int s = v0 + v1 + v2 + v3;
    lds[t] = s;
    __syncthreads();
    #pragma unroll
    for (int off = 1; off < 256; off <<= 1) {
        int y = (t >= off) ? lds[t - off] : 0;
        __syncthreads();
        lds[t] += y;
        __syncthreads();
    }
    int incl = lds[t];
    int excl = incl - s;
    if (base + 0 < N) rp[base + 0] = excl;
    if (base + 1 < N) rp[base + 1] = excl + v0;
    if (base + 2 < N) rp[base + 2] = excl + v0 + v1;
    if (base + 3 < N) rp[base + 3] = excl + v0 + v1 + v2;
    if (t == 255) bsum[blockIdx.x] = incl;
}

__global__ __launch_bounds__(256) void gcn_scan2(
    int* __restrict__ bsum, int* __restrict__ rp, int nb, int N, int E)
{
    __shared__ int lds[256];
    int t = threadIdx.x;
    int s = (t < nb) ? bsum[t] : 0;
    lds[t] = s;
    __syncthreads();
    #pragma unroll
    for (int off = 1; off < 256; off <<= 1) {
        int y = (t >= off) ? lds[t - off] : 0;
        __syncthreads();
        lds[t] += y;
        __syncthreads();
    }
    int incl = lds[t];
    if (t < nb) bsum[t] = incl - s;
    if (t == 0) rp[N] = E;
}

__global__ __launch_bounds__(256) void gcn_scan3(
    int* __restrict__ rp, int* __restrict__ cursor, const int* __restrict__ bsum, int N)
{
    int i = blockIdx.x * 256 + threadIdx.x;
    if (i >= N) return;
    int v = rp[i] + bsum[i >> 10];
    rp[i] = v;
    cursor[i] = v;
}

// ---------------- CSR fill: edge record (src, norm) as ONE 8B scattered write --
__global__ __launch_bounds__(256) void gcn_fill(
    const int* __restrict__ ei, const float* __restrict__ ew,
    const float* __restrict__ dis, int* __restrict__ cursor,
    uint2* __restrict__ edges, int E)
{
    int e = blockIdx.x * 256 + threadIdx.x;
    if (e >= E) return;
    int s = ei[e];
    int d = ei[E + e];
    float w = fabsf(ew[e]);
    float nrm = dis[s] * w * dis[d];
    int pos = atomicAdd(&cursor[d], 1);
    uint2 rec;
    rec.x = (uint_t)s;
    rec.y = __float_as_uint(nrm);
    edges[pos] = rec;
}

// ---------------- GEMM (fp32 X): Y[n,:FOUTP](bf16) = X[n,:FIN] @ W ----------------
template<int FIN, int FOUT, int FOUTP>
__global__ __launch_bounds__(256) void gcn_gemm_f32(
    const float* __restrict__ X, const float* __restrict__ W,
    ushort_t* __restrict__ Y, int N)
{
    int n = blockIdx.x * 256 + threadIdx.x;
    if (n >= N) return;
    const float4* xrow = (const float4*)(X + (size_t)n * FIN);
    float acc[FOUT];
    #pragma unroll
    for (int f = 0; f < FOUT; f++) acc[f] = 0.0f;

    for (int kb = 0; kb < FIN / 4; kb++) {
        float4 xv = xrow[kb];
        const float* xk4 = (const float*)&xv;
        #pragma unroll
        for (int kk = 0; kk < 4; kk++) {
            float xk = xk4[kk];
            const float* wr = W + (size_t)(kb * 4 + kk) * FOUT;
            #pragma unroll
            for (int f = 0; f < FOUT; f++) acc[f] += xk * wr[f];
        }
    }

    uint_t* y = (uint_t*)(Y + (size_t)n * FOUTP);
    #pragma unroll
    for (int fp = 0; fp < FOUT / 2; fp++) {
        uint_t v = (uint_t)f2b(acc[2 * fp]) | ((uint_t)f2b(acc[2 * fp + 1]) << 16);
        y[fp] = v;
    }
    #pragma unroll
    for (int fp = FOUT / 2; fp < FOUTP / 2; fp++) y[fp] = 0;
}

// ---------------- GEMM (bf16 X): Y[n,:FOUTP](bf16) = X[n,:FIN] @ W(fp32) ----------------
template<int FIN, int FOUT, int FOUTP>
__global__ __launch_bounds__(256) void gcn_gemm_b16(
    const ushort_t* __restrict__ X, const float* __restrict__ W,
    ushort_t* __restrict__ Y, int N)
{
    int n = blockIdx.x * 256 + threadIdx.x;
    if (n >= N) return;
    const uint4* xrow = (const uint4*)(X + (size_t)n * FIN);
    float acc[FOUT];
    #pragma unroll
    for (int f = 0; f < FOUT; f++) acc[f] = 0.0f;

    for (int kb = 0; kb < FIN / 8; kb++) {
        uint4 xv = xrow[kb];
        const uint_t* xw32 = (const uint_t*)&xv;
        #pragma unroll
        for (int kk = 0; kk < 8; kk++) {
            uint_t xpair = xw32[kk >> 1];
            float xk = b2f((kk & 1) ? (xpair >> 16) : (xpair & 0xffffu));
            const float* wr = W + (size_t)(kb * 8 + kk) * FOUT;
            #pragma unroll
            for (int f = 0; f < FOUT; f++) acc[f] += xk * wr[f];
        }
    }

    uint_t* y = (uint_t*)(Y + (size_t)n * FOUTP);
    #pragma unroll
    for (int fp = 0; fp < FOUT / 2; fp++) {
        uint_t v = (uint_t)f2b(acc[2 * fp]) | ((uint_t)f2b(acc[2 * fp + 1]) << 16);
        y[fp] = v;
    }
    #pragma unroll
    for (int fp = FOUT / 2; fp < FOUTP / 2; fp++) y[fp] = 0;
}

// ---------------- aggregation: H[n] = relu(b + dis[n]^2*XW[n] + sum_e nrm*XW[src]) ----
// LPN lanes per node, each lane owns a 4-bf16 chunk of the feature row
template<int FOUT, int FOUTP, int LPN, int BLK>
__global__ __launch_bounds__(BLK) void gcn_agg(
    const ushort_t* __restrict__ XW, const int* __restrict__ rp,
    const uint2* __restrict__ edges,
    const float* __restrict__ dis, const float* __restrict__ bias,
    ushort_t* __restrict__ H, int N)
{
    constexpr int NC = FOUTP / 4;
    int n = blockIdx.x * (BLK / LPN) + threadIdx.x / LPN;
    int c = threadIdx.x % LPN;
    if (n >= N) return;
    const uint2* xwc = (const uint2*)XW;

    int beg = rp[n], end = rp[n + 1];
    float a0 = 0.f, a1 = 0.f, a2 = 0.f, a3 = 0.f;
    for (int e = beg; e < end; e++) {
        uint2 ed = edges[e];
        int s = (int)ed.x;
        float nm = __uint_as_float(ed.y);
        uint2 v = xwc[(size_t)s * NC + c];
        a0 += nm * b2f(v.x & 0xffffu);
        a1 += nm * b2f(v.x >> 16);
        a2 += nm * b2f(v.y & 0xffffu);
        a3 += nm * b2f(v.y >> 16);
    }
    float d = dis[n];
    float sn = d * d;
    uint2 sv = xwc[(size_t)n * NC + c];
    a0 += sn * b2f(sv.x & 0xffffu);
    a1 += sn * b2f(sv.x >> 16);
    a2 += sn * b2f(sv.y & 0xffffu);
    a3 += sn * b2f(sv.y >> 16);

    int f0 = c * 4;
    float r0 = (f0 + 0 < FOUT) ? fmaxf(a0 + bias[f0 + 0], 0.f) : 0.f;
    float r1 = (f0 + 1 < FOUT) ? fmaxf(a1 + bias[f0 + 1], 0.f) : 0.f;
    float r2 = (f0 + 2 < FOUT) ? fmaxf(a2 + bias[f0 + 2], 0.f) : 0.f;
    float r3 = (f0 + 3 < FOUT) ? fmaxf(a3 + bias[f0 + 3], 0.f) : 0.f;

    uint2 o;
    o.x = (uint_t)f2b(r0) | ((uint_t)f2b(r1) << 16);
    o.y = (uint_t)f2b(r2) | ((uint_t)f2b(r3) << 16);
    ((uint2*)H)[(size_t)n * NC + c] = o;
}

// ---------------- mean-pool per graph + final linear + softmax ----------------
__global__ __launch_bounds__(256) void gcn_pool(
    const ushort_t* __restrict__ H, const int* __restrict__ batch,
    const float* __restrict__ Wf, const float* __restrict__ bf_,
    float* __restrict__ out, int N)
{
    __shared__ float pool[32];
    int g = blockIdx.x;
    int t = threadIdx.x;

    // lower_bound over sorted batch
    int lo = 0, hi = N;
    while (lo < hi) { int mid = (lo + hi) >> 1; if (batch[mid] < g) lo = mid + 1; else hi = mid; }
    int start = lo;
    lo = 0; hi = N;
    while (lo < hi) { int mid = (lo + hi) >> 1; if (batch[mid] < g + 1) lo = mid + 1; else hi = mid; }
    int end = lo;

    float acc[32];
    #pragma unroll
    for (int f = 0; f < 32; f++) acc[f] = 0.0f;
    for (int i = start + t; i < end; i += 256) {
        const uint2* hr = (const uint2*)H + (size_t)i * 8;
        #pragma unroll
        for (int q = 0; q < 8; q++) {
            uint2 v = hr[q];
            acc[4 * q + 0] += b2f(v.x & 0xffffu);
            acc[4 * q + 1] += b2f(v.x >> 16);
            acc[4 * q + 2] += b2f(v.y & 0xffffu);
            acc[4 * q + 3] += b2f(v.y >> 16);
        }
    }
    #pragma unroll
    for (int f = 0; f < 32; f++) {
        float v = acc[f];
        v += __shfl_down(v, 32, 64);
        v += __shfl_down(v, 16, 64);
        v += __shfl_down(v, 8, 64);
        v += __shfl_down(v, 4, 64);
        v += __shfl_down(v, 2, 64);
        v += __shfl_down(v, 1, 64);
        acc[f] = v;
    }
    if (t < 32) pool[t] = 0.0f;
    __syncthreads();
    if ((t & 63) == 0) {
        #pragma unroll
        for (int f = 0; f < 30; f++) atomicAdd(&pool[f], acc[f]);
    }
    __syncthreads();
    if (t == 0) {
        float inv = 1.0f / fmaxf((float)(end - start), 1.0f);
        float lg[10];
        #pragma unroll
        for (int j = 0; j < 10; j++) lg[j] = bf_[j];
        for (int f = 0; f < 30; f++) {
            float p = pool[f] * inv;
            #pragma unroll
            for (int j = 0; j < 10; j++) lg[j] += p * Wf[f * 10 + j];
        }
        float m = lg[0];
        #pragma unroll
        for (int j = 1; j < 10; j++) m = fmaxf(m, lg[j]);
        float s = 0.f;
        #pragma unroll
        for (int j = 0; j < 10; j++) { lg[j] = __expf(lg[j] - m); s += lg[j]; }
        float is = 1.0f / s;
        #pragma unroll
        for (int j = 0; j < 10; j++) out[g * 10 + j] = lg[j] * is;
    }
}

extern "C" void kernel_launch(void* const* d_in, const int* in_sizes, int n_in,
                              void* d_out, int out_size, void* d_ws, size_t ws_size,
                              hipStream_t stream) {
    (void)n_in; (void)out_size; (void)ws_size;
    const float* x   = (const float*)d_in[0];
    const int*   ei  = (const int*)d_in[1];
    const float* ew  = (const float*)d_in[2];
    const int*   bat = (const int*)d_in[3];
    const float* W1  = (const float*)d_in[4];
    const float* b1  = (const float*)d_in[5];
    const float* W2  = (const float*)d_in[6];
    const float* b2  = (const float*)d_in[7];
    const float* W3  = (const float*)d_in[8];
    const float* b3  = (const float*)d_in[9];
    const float* Wf  = (const float*)d_in[10];
    const float* bf_ = (const float*)d_in[11];
    float* out = (float*)d_out;

    const int N = in_sizes[3];       // 100000
    const int E = in_sizes[2];       // 3200000
    const size_t N4 = (size_t)N * 4;

    char* wsb = (char*)d_ws;
    size_t o = 0;
    auto take = [&](size_t bytes) -> char* {
        char* p = wsb + o;
        o += (bytes + 255) & ~(size_t)255;
        return p;
    };
    u64_t*    dh     = (u64_t*)take((size_t)N * 8);      // zeroed each call
    float*    dis    = (float*)take(N4);
    int*      cnt    = (int*)take(N4);
    int*      rp     = (int*)take((size_t)(N + 1) * 4);
    int*      cursor = (int*)take(N4);
    int*      bsum   = (int*)take(4096);
    uint2*    edges  = (uint2*)take((size_t)E * 8);
    ushort_t* xw     = (ushort_t*)take((size_t)N * 96 * 2);
    ushort_t* h      = (ushort_t*)take((size_t)N * 96 * 2);

    const int gE = (E + 255) / 256;
    const int gN = (N + 255) / 256;
    const int nb = (N + 1023) / 1024;

    // zero the fused histogram
    hipMemsetAsync(dh, 0, (size_t)N * 8, stream);

    // normalization precompute + CSR build
    gcn_deg_hist<<<gE, 256, 0, stream>>>(ei, ew, dh, E);
    gcn_dis<<<gN, 256, 0, stream>>>(dh, dis, cnt, N);
    gcn_scan1<<<nb, 256, 0, stream>>>(cnt, rp, bsum, N);
    gcn_scan2<<<1, 256, 0, stream>>>(bsum, rp, nb, N, E);
    gcn_scan3<<<gN, 256, 0, stream>>>(rp, cursor, bsum, N);
    gcn_fill<<<gE, 256, 0, stream>>>(ei, ew, dis, cursor, edges, E);

    // layer 1: x[.,128](fp32) -> xw[.,96](bf16) -> h[.,96](bf16)
    gcn_gemm_f32<128, 96, 96><<<gN, 256, 0, stream>>>(x, W1, xw, N);
    gcn_agg<96, 96, 24, 192><<<(N + 7) / 8, 192, 0, stream>>>(xw, rp, edges, dis, b1, h, N);

    // layer 2: h[.,96] -> xw[.,96] -> h[.,96]
    gcn_gemm_b16<96, 96, 96><<<gN, 256, 0, stream>>>(h, W2, xw, N);
    gcn_agg<96, 96, 24, 192><<<(N + 7) / 8, 192, 0, stream>>>(xw, rp, edges, dis, b2, h, N);

    // layer 3: h[.,96] -> xw[.,32 (30 used)] -> h[.,32]
    gcn_gemm_b16<96, 30, 32><<<gN, 256, 0, stream>>>(h, W3, xw, N);
    gcn_agg<30, 32, 8, 256><<<(N + 31) / 32, 256, 0, stream>>>(xw, rp, edges, dis, b3, h, N);

    // mean pool + classifier + softmax
    gcn_pool<<<256, 256, 0, stream>>>(h, bat, Wf, bf_, out, N);
}

// Round 4
// 830.180 us; speedup vs baseline: 1.5696x; 1.3183x over previous
//
#include <hip/hip_runtime.h>
#include <hip/hip_bf16.h>

typedef unsigned short ushort_t;
typedef unsigned int uint_t;
typedef unsigned long long u64_t;

typedef __attribute__((ext_vector_type(8))) short bf16x8;   // 8 bf16 (4 VGPRs)
typedef __attribute__((ext_vector_type(4))) float floatx4;  // MFMA C/D

#define DI __device__ __forceinline__

// bf16 bits -> f32
DI float b2f(uint_t lo16) {
    union { uint_t u; float f; } v; v.u = lo16 << 16; return v.f;
}
// f32 -> bf16 bits, round-to-nearest-even
DI ushort_t f2b(float f) {
    union { float f; uint_t u; } v; v.f = f;
    uint_t u = v.u;
    uint_t r = (u + 0x7fffu + ((u >> 16) & 1u)) >> 16;
    return (ushort_t)r;
}

// ---------------- fused degree+count histogram: one u64 atomic per edge ------
// dh[d] += (1<<40) | round(|w| * 2^23)
__global__ __launch_bounds__(256) void gcn_deg_hist(
    const int* __restrict__ ei, const float* __restrict__ ew,
    u64_t* __restrict__ dh, int E)
{
    int e = blockIdx.x * 256 + threadIdx.x;
    if (e >= E) return;
    int d = ei[E + e];
    float w = fabsf(ew[e]);
    u64_t v = (1ULL << 40) | (u64_t)__float2uint_rn(w * 8388608.0f);
    atomicAdd(&dh[d], v);
}

// dh -> dis = rsqrt(deg+1), cnt
__global__ __launch_bounds__(256) void gcn_dis(
    const u64_t* __restrict__ dh, float* __restrict__ dis,
    int* __restrict__ cnt, int N)
{
    int i = blockIdx.x * 256 + threadIdx.x;
    if (i >= N) return;
    u64_t v = dh[i];
    cnt[i] = (int)(v >> 40);
    float deg = (float)(uint_t)(v & 0xFFFFFFFFFFULL) * (1.0f / 8388608.0f);
    dis[i] = rsqrtf(deg + 1.0f);
}

// ---------------- exclusive scan (3 kernels, 1024 elems/block) ----------------
__global__ __launch_bounds__(256) void gcn_scan1(
    const int* __restrict__ cnt, int* __restrict__ rp, int* __restrict__ bsum, int N)
{
    __shared__ int lds[256];
    int t = threadIdx.x;
    int base = blockIdx.x * 1024 + t * 4;
    int v0 = (base + 0 < N) ? cnt[base + 0] : 0;
    int v1 = (base + 1 < N) ? cnt[base + 1] : 0;
    int v2 = (base + 2 < N) ? cnt[base + 2] : 0;
    int v3 = (base + 3 < N) ? cnt[base + 3] : 0;
    int s = v0 + v1 + v2 + v3;
    lds[t] = s;
    __syncthreads();
    #pragma unroll
    for (int off = 1; off < 256; off <<= 1) {
        int y = (t >= off) ? lds[t - off] : 0;
        __syncthreads();
        lds[t] += y;
        __syncthreads();
    }
    int incl = lds[t];
    int excl = incl - s;
    if (base + 0 < N) rp[base + 0] = excl;
    if (base + 1 < N) rp[base + 1] = excl + v0;
    if (base + 2 < N) rp[base + 2] = excl + v0 + v1;
    if (base + 3 < N) rp[base + 3] = excl + v0 + v1 + v2;
    if (t == 255) bsum[blockIdx.x] = incl;
}

__global__ __launch_bounds__(256) void gcn_scan2(
    int* __restrict__ bsum, int* __restrict__ rp, int nb, int N, int E)
{
    __shared__ int lds[256];
    int t = threadIdx.x;
    int s = (t < nb) ? bsum[t] : 0;
    lds[t] = s;
    __syncthreads();
    #pragma unroll
    for (int off = 1; off < 256; off <<= 1) {
        int y = (t >= off) ? lds[t - off] : 0;
        __syncthreads();
        lds[t] += y;
        __syncthreads();
    }
    int incl = lds[t];
    if (t < nb) bsum[t] = incl - s;
    if (t == 0) rp[N] = E;
}

__global__ __launch_bounds__(256) void gcn_scan3(
    int* __restrict__ rp, int* __restrict__ cursor, const int* __restrict__ bsum, int N)
{
    int i = blockIdx.x * 256 + threadIdx.x;
    if (i >= N) return;
    int v = rp[i] + bsum[i >> 10];
    rp[i] = v;
    cursor[i] = v;
}

// ---------------- CSR fill: edge record (src, norm) as ONE 8B scattered write --
__global__ __launch_bounds__(256) void gcn_fill(
    const int* __restrict__ ei, const float* __restrict__ ew,
    const float* __restrict__ dis, int* __restrict__ cursor,
    uint2* __restrict__ edges, int E)
{
    int e = blockIdx.x * 256 + threadIdx.x;
    if (e >= E) return;
    int s = ei[e];
    int d = ei[E + e];
    float w = fabsf(ew[e]);
    float nrm = dis[s] * w * dis[d];
    int pos = atomicAdd(&cursor[d], 1);
    uint2 rec;
    rec.x = (uint_t)s;
    rec.y = __float_as_uint(nrm);
    edges[pos] = rec;
}

// ---------------- weight transpose + bf16 convert (once per call, tiny) -------
// Wt[n][k] = bf16(W[k][n]); layer3 padded to 32 rows (rows 30,31 zero)
__global__ __launch_bounds__(256) void gcn_wt(
    const float* __restrict__ W1, const float* __restrict__ W2,
    const float* __restrict__ W3,
    ushort_t* __restrict__ Wt1, ushort_t* __restrict__ Wt2,
    ushort_t* __restrict__ Wt3)
{
    int i = blockIdx.x * 256 + threadIdx.x;
    if (i < 96 * 128) {                       // layer 1: Wt1[96][128]
        int n = i / 128, k = i % 128;
        Wt1[i] = f2b(W1[k * 96 + n]);
    }
    if (i < 96 * 96) {                        // layer 2: Wt2[96][96]
        int n = i / 96, k = i % 96;
        Wt2[i] = f2b(W2[k * 96 + n]);
    }
    if (i < 32 * 96) {                        // layer 3: Wt3[32][96], pad rows 30,31
        int n = i / 96, k = i % 96;
        Wt3[i] = f2b((n < 30) ? W3[k * 30 + n] : 0.0f);
    }
}

// ---------------- MFMA GEMM: Y[64-row tile, FOUTP] = X @ W ---------------------
// block = 256 thr (4 waves); wave w computes rows [tile+16w, tile+16w+16) x FOUTP cols.
// 16x16x32 bf16 MFMA. Verified layouts: A[m=lane&15][k=quad*8+j],
// B[k=quad*8+j][n=lane&15], C/D col=lane&15, row=quad*4+reg.
// LDS stride padded +8 shorts to spread banks.
template<int K, int FOUT, int NTR, int FOUTP, bool XF32>
__global__ __launch_bounds__(256) void gcn_gemm_mfma(
    const void* __restrict__ Xv, const ushort_t* __restrict__ Wt,
    ushort_t* __restrict__ Y, int N)
{
    constexpr int KS = K + 8;          // LDS row stride in shorts (byte stride %16==0)
    constexpr int KT = K / 32;         // MFMA K-steps
    constexpr int NT = NTR / 16;       // N-tiles
    __shared__ ushort_t xs[64 * KS];
    __shared__ ushort_t ws[NTR * KS];

    int t = threadIdx.x;
    int mbase = blockIdx.x * 64;

    // stage Wt -> LDS (coalesced 16B)
    {
        constexpr int TOT = NTR * (K / 8);
        const uint4* wg = (const uint4*)Wt;
        for (int i = t; i < TOT; i += 256) {
            int r = i / (K / 8), c8 = i % (K / 8);
            *(uint4*)(ws + r * KS + c8 * 8) = wg[i];
        }
    }
    // stage X tile -> LDS
    if (XF32) {
        const float* X = (const float*)Xv;
        constexpr int TOT = 64 * (K / 4);
        for (int i = t; i < TOT; i += 256) {
            int row = i / (K / 4), c4 = i % (K / 4);
            int rg = mbase + row; if (rg >= N) rg = N - 1;
            float4 v = *(const float4*)(X + (size_t)rg * K + c4 * 4);
            uint2 pv;
            pv.x = (uint_t)f2b(v.x) | ((uint_t)f2b(v.y) << 16);
            pv.y = (uint_t)f2b(v.z) | ((uint_t)f2b(v.w) << 16);
            *(uint2*)(xs + row * KS + c4 * 4) = pv;
        }
    } else {
        const ushort_t* X = (const ushort_t*)Xv;
        constexpr int TOT = 64 * (K / 8);
        for (int i = t; i < TOT; i += 256) {
            int row = i / (K / 8), c8 = i % (K / 8);
            int rg = mbase + row; if (rg >= N) rg = N - 1;
            *(uint4*)(xs + row * KS + c8 * 8) = *(const uint4*)(X + (size_t)rg * K + c8 * 8);
        }
    }
    __syncthreads();

    int wave = t >> 6;
    int lane = t & 63;
    int l15 = lane & 15, quad = lane >> 4;

    bf16x8 af[KT];
    #pragma unroll
    for (int kt = 0; kt < KT; kt++)
        af[kt] = *(const bf16x8*)(xs + (wave * 16 + l15) * KS + kt * 32 + quad * 8);

    floatx4 acc[NT];
    #pragma unroll
    for (int nt = 0; nt < NT; nt++) acc[nt] = (floatx4){0.f, 0.f, 0.f, 0.f};

    #pragma unroll
    for (int nt = 0; nt < NT; nt++) {
        #pragma unroll
        for (int kt = 0; kt < KT; kt++) {
            bf16x8 bfr = *(const bf16x8*)(ws + (nt * 16 + l15) * KS + kt * 32 + quad * 8);
            acc[nt] = __builtin_amdgcn_mfma_f32_16x16x32_bf16(af[kt], bfr, acc[nt], 0, 0, 0);
        }
    }

    // store C: col=lane&15, row=quad*4+reg
    #pragma unroll
    for (int nt = 0; nt < NT; nt++) {
        int col = nt * 16 + l15;
        #pragma unroll
        for (int r = 0; r < 4; r++) {
            int row = mbase + wave * 16 + quad * 4 + r;
            if (row < N) {
                float v = (col < FOUT) ? acc[nt][r] : 0.0f;
                Y[(size_t)row * FOUTP + col] = f2b(v);
            }
        }
    }
}

// ---------------- aggregation: H[n] = relu(b + dis[n]^2*XW[n] + sum_e nrm*XW[src]) ----
template<int FOUT, int FOUTP, int LPN, int BLK>
__global__ __launch_bounds__(BLK) void gcn_agg(
    const ushort_t* __restrict__ XW, const int* __restrict__ rp,
    const uint2* __restrict__ edges,
    const float* __restrict__ dis, const float* __restrict__ bias,
    ushort_t* __restrict__ H, int N)
{
    constexpr int NC = FOUTP / 4;
    int n = blockIdx.x * (BLK / LPN) + threadIdx.x / LPN;
    int c = threadIdx.x % LPN;
    if (n >= N) return;
    const uint2* xwc = (const uint2*)XW;

    int beg = rp[n], end = rp[n + 1];
    float a0 = 0.f, a1 = 0.f, a2 = 0.f, a3 = 0.f;
    for (int e = beg; e < end; e++) {
        uint2 ed = edges[e];
        int s = (int)ed.x;
        float nm = __uint_as_float(ed.y);
        uint2 v = xwc[(size_t)s * NC + c];
        a0 += nm * b2f(v.x & 0xffffu);
        a1 += nm * b2f(v.x >> 16);
        a2 += nm * b2f(v.y & 0xffffu);
        a3 += nm * b2f(v.y >> 16);
    }
    float d = dis[n];
    float sn = d * d;
    uint2 sv = xwc[(size_t)n * NC + c];
    a0 += sn * b2f(sv.x & 0xffffu);
    a1 += sn * b2f(sv.x >> 16);
    a2 += sn * b2f(sv.y & 0xffffu);
    a3 += sn * b2f(sv.y >> 16);

    int f0 = c * 4;
    float r0 = (f0 + 0 < FOUT) ? fmaxf(a0 + bias[f0 + 0], 0.f) : 0.f;
    float r1 = (f0 + 1 < FOUT) ? fmaxf(a1 + bias[f0 + 1], 0.f) : 0.f;
    float r2 = (f0 + 2 < FOUT) ? fmaxf(a2 + bias[f0 + 2], 0.f) : 0.f;
    float r3 = (f0 + 3 < FOUT) ? fmaxf(a3 + bias[f0 + 3], 0.f) : 0.f;

    uint2 o;
    o.x = (uint_t)f2b(r0) | ((uint_t)f2b(r1) << 16);
    o.y = (uint_t)f2b(r2) | ((uint_t)f2b(r3) << 16);
    ((uint2*)H)[(size_t)n * NC + c] = o;
}

// ---------------- mean-pool per graph + final linear + softmax ----------------
__global__ __launch_bounds__(256) void gcn_pool(
    const ushort_t* __restrict__ H, const int* __restrict__ batch,
    const float* __restrict__ Wf, const float* __restrict__ bf_,
    float* __restrict__ out, int N)
{
    __shared__ float pool[32];
    int g = blockIdx.x;
    int t = threadIdx.x;

    int lo = 0, hi = N;
    while (lo < hi) { int mid = (lo + hi) >> 1; if (batch[mid] < g) lo = mid + 1; else hi = mid; }
    int start = lo;
    lo = 0; hi = N;
    while (lo < hi) { int mid = (lo + hi) >> 1; if (batch[mid] < g + 1) lo = mid + 1; else hi = mid; }
    int end = lo;

    float acc[32];
    #pragma unroll
    for (int f = 0; f < 32; f++) acc[f] = 0.0f;
    for (int i = start + t; i < end; i += 256) {
        const uint2* hr = (const uint2*)H + (size_t)i * 8;
        #pragma unroll
        for (int q = 0; q < 8; q++) {
            uint2 v = hr[q];
            acc[4 * q + 0] += b2f(v.x & 0xffffu);
            acc[4 * q + 1] += b2f(v.x >> 16);
            acc[4 * q + 2] += b2f(v.y & 0xffffu);
            acc[4 * q + 3] += b2f(v.y >> 16);
        }
    }
    #pragma unroll
    for (int f = 0; f < 32; f++) {
        float v = acc[f];
        v += __shfl_down(v, 32, 64);
        v += __shfl_down(v, 16, 64);
        v += __shfl_down(v, 8, 64);
        v += __shfl_down(v, 4, 64);
        v += __shfl_down(v, 2, 64);
        v += __shfl_down(v, 1, 64);
        acc[f] = v;
    }
    if (t < 32) pool[t] = 0.0f;
    __syncthreads();
    if ((t & 63) == 0) {
        #pragma unroll
        for (int f = 0; f < 30; f++) atomicAdd(&pool[f], acc[f]);
    }
    __syncthreads();
    if (t == 0) {
        float inv = 1.0f / fmaxf((float)(end - start), 1.0f);
        float lg[10];
        #pragma unroll
        for (int j = 0; j < 10; j++) lg[j] = bf_[j];
        for (int f = 0; f < 30; f++) {
            float p = pool[f] * inv;
            #pragma unroll
            for (int j = 0; j < 10; j++) lg[j] += p * Wf[f * 10 + j];
        }
        float m = lg[0];
        #pragma unroll
        for (int j = 1; j < 10; j++) m = fmaxf(m, lg[j]);
        float s = 0.f;
        #pragma unroll
        for (int j = 0; j < 10; j++) { lg[j] = __expf(lg[j] - m); s += lg[j]; }
        float is = 1.0f / s;
        #pragma unroll
        for (int j = 0; j < 10; j++) out[g * 10 + j] = lg[j] * is;
    }
}

extern "C" void kernel_launch(void* const* d_in, const int* in_sizes, int n_in,
                              void* d_out, int out_size, void* d_ws, size_t ws_size,
                              hipStream_t stream) {
    (void)n_in; (void)out_size; (void)ws_size;
    const float* x   = (const float*)d_in[0];
    const int*   ei  = (const int*)d_in[1];
    const float* ew  = (const float*)d_in[2];
    const int*   bat = (const int*)d_in[3];
    const float* W1  = (const float*)d_in[4];
    const float* b1  = (const float*)d_in[5];
    const float* W2  = (const float*)d_in[6];
    const float* b2  = (const float*)d_in[7];
    const float* W3  = (const float*)d_in[8];
    const float* b3  = (const float*)d_in[9];
    const float* Wf  = (const float*)d_in[10];
    const float* bf_ = (const float*)d_in[11];
    float* out = (float*)d_out;

    const int N = in_sizes[3];       // 100000
    const int E = in_sizes[2];       // 3200000
    const size_t N4 = (size_t)N * 4;

    char* wsb = (char*)d_ws;
    size_t o = 0;
    auto take = [&](size_t bytes) -> char* {
        char* p = wsb + o;
        o += (bytes + 255) & ~(size_t)255;
        return p;
    };
    u64_t*    dh     = (u64_t*)take((size_t)N * 8);      // zeroed each call
    float*    dis    = (float*)take(N4);
    int*      cnt    = (int*)take(N4);
    int*      rp     = (int*)take((size_t)(N + 1) * 4);
    int*      cursor = (int*)take(N4);
    int*      bsum   = (int*)take(4096);
    uint2*    edges  = (uint2*)take((size_t)E * 8);
    ushort_t* xw     = (ushort_t*)take((size_t)N * 96 * 2);
    ushort_t* h      = (ushort_t*)take((size_t)N * 96 * 2);
    ushort_t* Wt1    = (ushort_t*)take(96 * 128 * 2);
    ushort_t* Wt2    = (ushort_t*)take(96 * 96 * 2);
    ushort_t* Wt3    = (ushort_t*)take(32 * 96 * 2);

    const int gE = (E + 255) / 256;
    const int gN = (N + 255) / 256;
    const int gM = (N + 63) / 64;
    const int nb = (N + 1023) / 1024;

    hipMemsetAsync(dh, 0, (size_t)N * 8, stream);

    // normalization precompute + CSR build + weight transpose
    gcn_deg_hist<<<gE, 256, 0, stream>>>(ei, ew, dh, E);
    gcn_wt<<<48, 256, 0, stream>>>(W1, W2, W3, Wt1, Wt2, Wt3);
    gcn_dis<<<gN, 256, 0, stream>>>(dh, dis, cnt, N);
    gcn_scan1<<<nb, 256, 0, stream>>>(cnt, rp, bsum, N);
    gcn_scan2<<<1, 256, 0, stream>>>(bsum, rp, nb, N, E);
    gcn_scan3<<<gN, 256, 0, stream>>>(rp, cursor, bsum, N);
    gcn_fill<<<gE, 256, 0, stream>>>(ei, ew, dis, cursor, edges, E);

    // layer 1: x[.,128](fp32) -> xw[.,96](bf16) -> h[.,96](bf16)
    gcn_gemm_mfma<128, 96, 96, 96, true><<<gM, 256, 0, stream>>>(x, Wt1, xw, N);
    gcn_agg<96, 96, 24, 192><<<(N + 7) / 8, 192, 0, stream>>>(xw, rp, edges, dis, b1, h, N);

    // layer 2
    gcn_gemm_mfma<96, 96, 96, 96, false><<<gM, 256, 0, stream>>>(h, Wt2, xw, N);
    gcn_agg<96, 96, 24, 192><<<(N + 7) / 8, 192, 0, stream>>>(xw, rp, edges, dis, b2, h, N);

    // layer 3 (FOUT=30 padded to 32)
    gcn_gemm_mfma<96, 30, 32, 32, false><<<gM, 256, 0, stream>>>(h, Wt3, xw, N);
    gcn_agg<30, 32, 8, 256><<<(N + 31) / 32, 256, 0, stream>>>(xw, rp, edges, dis, b3, h, N);

    // mean pool + classifier + softmax
    gcn_pool<<<256, 256, 0, stream>>>(h, bat, Wf, bf_, out, N);
}

// Round 5
// 693.703 us; speedup vs baseline: 1.8784x; 1.1967x over previous
//
#include <hip/hip_runtime.h>
#include <hip/hip_bf16.h>

typedef unsigned short ushort_t;
typedef unsigned int uint_t;

typedef __attribute__((ext_vector_type(8))) short bf16x8;   // 8 bf16 (4 VGPRs)
typedef __attribute__((ext_vector_type(4))) float floatx4;  // MFMA C/D

#define DI __device__ __forceinline__

// NOTE: record packing uses 17 bits for src -> requires N < 131072. (N=100000)
#define NPB 128          // nodes per bucket
#define NBMAX 1024       // max buckets (N <= 131072)

// bf16 bits -> f32
DI float b2f(uint_t lo16) {
    union { uint_t u; float f; } v; v.u = lo16 << 16; return v.f;
}
// f32 -> bf16 bits, round-to-nearest-even
DI ushort_t f2b(float f) {
    union { float f; uint_t u; } v; v.f = f;
    uint_t u = v.u;
    uint_t r = (u + 0x7fffu + ((u >> 16) & 1u)) >> 16;
    return (ushort_t)r;
}

// ---------------- P1: bucket histogram (LDS-binned; ~77k global atomics) -----
__global__ __launch_bounds__(1024) void gcn_bhist(
    const int* __restrict__ ei, int* __restrict__ bkt_cnt, int E, int NB)
{
    __shared__ int hist[NBMAX];
    int t = threadIdx.x;
    for (int b = t; b < NB; b += 1024) hist[b] = 0;
    __syncthreads();
    int base = blockIdx.x * 32768;
    int lim = min(32768, E - base);
    for (int i = t; i < lim; i += 1024) {
        int d = ei[(size_t)E + base + i];
        atomicAdd(&hist[d >> 7], 1);
    }
    __syncthreads();
    for (int b = t; b < NB; b += 1024) {
        int c = hist[b];
        if (c) atomicAdd(&bkt_cnt[b], c);
    }
}

// ---------------- P2: scan bucket counts -> bases/cursors --------------------
__global__ __launch_bounds__(256) void gcn_bscan(
    const int* __restrict__ bkt_cnt, int* __restrict__ bkt_base,
    int* __restrict__ bkt_cursor, int* __restrict__ rp, int NB, int N, int E)
{
    __shared__ int lds[256];
    int t = threadIdx.x;
    int v[4]; int s = 0;
    #pragma unroll
    for (int j = 0; j < 4; j++) {
        int b = t * 4 + j;
        v[j] = (b < NB) ? bkt_cnt[b] : 0;
        s += v[j];
    }
    lds[t] = s;
    __syncthreads();
    #pragma unroll
    for (int off = 1; off < 256; off <<= 1) {
        int y = (t >= off) ? lds[t - off] : 0;
        __syncthreads();
        lds[t] += y;
        __syncthreads();
    }
    int run = lds[t] - s;
    #pragma unroll
    for (int j = 0; j < 4; j++) {
        int b = t * 4 + j;
        if (b < NB) { bkt_base[b] = run; bkt_cursor[b] = run; }
        run += v[j];
    }
    if (t == 255) { bkt_base[NB] = E; rp[N] = E; }
}

// ---------------- P3: scatter records into bucket regions --------------------
// record: x = src | (dst&127)<<17 ; y = |w| (f32 bits). Per-edge atomics are LDS.
__global__ __launch_bounds__(1024) void gcn_bscatter(
    const int* __restrict__ ei, const float* __restrict__ ew,
    int* __restrict__ bkt_cursor, uint2* __restrict__ stage, int E, int NB)
{
    __shared__ int hist[NBMAX];
    __shared__ int cur[NBMAX];
    int t = threadIdx.x;
    for (int b = t; b < NB; b += 1024) hist[b] = 0;
    __syncthreads();
    int base = blockIdx.x * 32768;
    int lim = min(32768, E - base);
    for (int i = t; i < lim; i += 1024) {
        int d = ei[(size_t)E + base + i];
        atomicAdd(&hist[d >> 7], 1);
    }
    __syncthreads();
    for (int b = t; b < NB; b += 1024) {
        int c = hist[b];
        cur[b] = c ? atomicAdd(&bkt_cursor[b], c) : 0;
    }
    __syncthreads();
    for (int i = t; i < lim; i += 1024) {
        int e = base + i;
        int s = ei[e];
        int d = ei[(size_t)E + e];
        float w = fabsf(ew[e]);
        int pos = atomicAdd(&cur[d >> 7], 1);
        uint2 rec;
        rec.x = (uint_t)s | ((uint_t)(d & 127) << 17);
        rec.y = __float_as_uint(w);
        stage[pos] = rec;
    }
}

// ---------------- P4: per-bucket counting sort by node + deg/dis/rp ----------
__global__ __launch_bounds__(256) void gcn_bsort(
    const uint2* __restrict__ stage, uint2* __restrict__ edges,
    const int* __restrict__ bkt_base, int* __restrict__ rp,
    float* __restrict__ dis, int N)
{
    int b = blockIdx.x;
    int base = bkt_base[b], end = bkt_base[b + 1];
    int cnte = end - base;
    int n0 = b << 7;
    __shared__ int cnt[NPB];
    __shared__ float wsum[NPB];
    __shared__ int lds[NPB];
    __shared__ int cur[NPB];
    int t = threadIdx.x;
    if (t < NPB) { cnt[t] = 0; wsum[t] = 0.0f; }
    __syncthreads();
    for (int i = t; i < cnte; i += 256) {
        uint2 r = stage[base + i];
        int dl = (r.x >> 17) & 127;
        atomicAdd(&cnt[dl], 1);
        atomicAdd(&wsum[dl], __uint_as_float(r.y));
    }
    __syncthreads();
    if (t < NPB) lds[t] = cnt[t];
    __syncthreads();
    #pragma unroll
    for (int o = 1; o < NPB; o <<= 1) {
        int y = (t >= o && t < NPB) ? lds[t - o] : 0;
        __syncthreads();
        if (t < NPB) lds[t] += y;
        __syncthreads();
    }
    if (t < NPB) {
        int excl = lds[t] - cnt[t];
        cur[t] = base + excl;
        int n = n0 + t;
        if (n < N) {
            rp[n] = base + excl;
            dis[n] = rsqrtf(wsum[t] + 1.0f);
        }
    }
    __syncthreads();
    for (int i = t; i < cnte; i += 256) {
        uint2 r = stage[base + i];
        int dl = (r.x >> 17) & 127;
        int pos = atomicAdd(&cur[dl], 1);
        edges[pos] = r;
    }
}

// ---------------- P5: rewrite w -> nrm = dis[src]*|w|*dis[dst] ---------------
__global__ __launch_bounds__(256) void gcn_bnorm(
    uint2* __restrict__ edges, const int* __restrict__ bkt_base,
    const float* __restrict__ dis, int N)
{
    int b = blockIdx.x;
    int base = bkt_base[b], end = bkt_base[b + 1];
    int n0 = b << 7;
    __shared__ float ldis[NPB];
    int t = threadIdx.x;
    if (t < NPB) { int n = n0 + t; ldis[t] = (n < N) ? dis[n] : 0.0f; }
    __syncthreads();
    for (int i = t; i < end - base; i += 256) {
        uint2 r = edges[base + i];
        int s = r.x & 0x1FFFF;
        float w = __uint_as_float(r.y);
        float nm = dis[s] * w * ldis[(r.x >> 17) & 127];
        r.y = __float_as_uint(nm);
        edges[base + i] = r;
    }
}

// ---------------- weight transpose + bf16 convert (once per call, tiny) -------
__global__ __launch_bounds__(256) void gcn_wt(
    const float* __restrict__ W1, const float* __restrict__ W2,
    const float* __restrict__ W3,
    ushort_t* __restrict__ Wt1, ushort_t* __restrict__ Wt2,
    ushort_t* __restrict__ Wt3)
{
    int i = blockIdx.x * 256 + threadIdx.x;
    if (i < 96 * 128) {                       // layer 1: Wt1[96][128]
        int n = i / 128, k = i % 128;
        Wt1[i] = f2b(W1[k * 96 + n]);
    }
    if (i < 96 * 96) {                        // layer 2: Wt2[96][96]
        int n = i / 96, k = i % 96;
        Wt2[i] = f2b(W2[k * 96 + n]);
    }
    if (i < 32 * 96) {                        // layer 3: Wt3[32][96], pad rows 30,31
        int n = i / 96, k = i % 96;
        Wt3[i] = f2b((n < 30) ? W3[k * 30 + n] : 0.0f);
    }
}

// ---------------- MFMA GEMM: Y[64-row tile, FOUTP] = X @ W ---------------------
template<int K, int FOUT, int NTR, int FOUTP, bool XF32>
__global__ __launch_bounds__(256) void gcn_gemm_mfma(
    const void* __restrict__ Xv, const ushort_t* __restrict__ Wt,
    ushort_t* __restrict__ Y, int N)
{
    constexpr int KS = K + 8;
    constexpr int KT = K / 32;
    constexpr int NT = NTR / 16;
    __shared__ ushort_t xs[64 * KS];
    __shared__ ushort_t ws[NTR * KS];

    int t = threadIdx.x;
    int mbase = blockIdx.x * 64;

    {
        constexpr int TOT = NTR * (K / 8);
        const uint4* wg = (const uint4*)Wt;
        for (int i = t; i < TOT; i += 256) {
            int r = i / (K / 8), c8 = i % (K / 8);
            *(uint4*)(ws + r * KS + c8 * 8) = wg[i];
        }
    }
    if (XF32) {
        const float* X = (const float*)Xv;
        constexpr int TOT = 64 * (K / 4);
        for (int i = t; i < TOT; i += 256) {
            int row = i / (K / 4), c4 = i % (K / 4);
            int rg = mbase + row; if (rg >= N) rg = N - 1;
            float4 v = *(const float4*)(X + (size_t)rg * K + c4 * 4);
            uint2 pv;
            pv.x = (uint_t)f2b(v.x) | ((uint_t)f2b(v.y) << 16);
            pv.y = (uint_t)f2b(v.z) | ((uint_t)f2b(v.w) << 16);
            *(uint2*)(xs + row * KS + c4 * 4) = pv;
        }
    } else {
        const ushort_t* X = (const ushort_t*)Xv;
        constexpr int TOT = 64 * (K / 8);
        for (int i = t; i < TOT; i += 256) {
            int row = i / (K / 8), c8 = i % (K / 8);
            int rg = mbase + row; if (rg >= N) rg = N - 1;
            *(uint4*)(xs + row * KS + c8 * 8) = *(const uint4*)(X + (size_t)rg * K + c8 * 8);
        }
    }
    __syncthreads();

    int wave = t >> 6;
    int lane = t & 63;
    int l15 = lane & 15, quad = lane >> 4;

    bf16x8 af[KT];
    #pragma unroll
    for (int kt = 0; kt < KT; kt++)
        af[kt] = *(const bf16x8*)(xs + (wave * 16 + l15) * KS + kt * 32 + quad * 8);

    floatx4 acc[NT];
    #pragma unroll
    for (int nt = 0; nt < NT; nt++) acc[nt] = (floatx4){0.f, 0.f, 0.f, 0.f};

    #pragma unroll
    for (int nt = 0; nt < NT; nt++) {
        #pragma unroll
        for (int kt = 0; kt < KT; kt++) {
            bf16x8 bfr = *(const bf16x8*)(ws + (nt * 16 + l15) * KS + kt * 32 + quad * 8);
            acc[nt] = __builtin_amdgcn_mfma_f32_16x16x32_bf16(af[kt], bfr, acc[nt], 0, 0, 0);
        }
    }

    #pragma unroll
    for (int nt = 0; nt < NT; nt++) {
        int col = nt * 16 + l15;
        #pragma unroll
        for (int r = 0; r < 4; r++) {
            int row = mbase + wave * 16 + quad * 4 + r;
            if (row < N) {
                float v = (col < FOUT) ? acc[nt][r] : 0.0f;
                Y[(size_t)row * FOUTP + col] = f2b(v);
            }
        }
    }
}

// ---------------- aggregation: H[n] = relu(b + dis[n]^2*XW[n] + sum_e nrm*XW[src]) ----
template<int FOUT, int FOUTP, int LPN, int BLK>
__global__ __launch_bounds__(BLK) void gcn_agg(
    const ushort_t* __restrict__ XW, const int* __restrict__ rp,
    const uint2* __restrict__ edges,
    const float* __restrict__ dis, const float* __restrict__ bias,
    ushort_t* __restrict__ H, int N)
{
    constexpr int NC = FOUTP / 4;
    int n = blockIdx.x * (BLK / LPN) + threadIdx.x / LPN;
    int c = threadIdx.x % LPN;
    if (n >= N) return;
    const uint2* xwc = (const uint2*)XW;

    int beg = rp[n], end = rp[n + 1];
    float a0 = 0.f, a1 = 0.f, a2 = 0.f, a3 = 0.f;
    for (int e = beg; e < end; e++) {
        uint2 ed = edges[e];
        int s = (int)(ed.x & 0x1FFFF);
        float nm = __uint_as_float(ed.y);
        uint2 v = xwc[(size_t)s * NC + c];
        a0 += nm * b2f(v.x & 0xffffu);
        a1 += nm * b2f(v.x >> 16);
        a2 += nm * b2f(v.y & 0xffffu);
        a3 += nm * b2f(v.y >> 16);
    }
    float d = dis[n];
    float sn = d * d;
    uint2 sv = xwc[(size_t)n * NC + c];
    a0 += sn * b2f(sv.x & 0xffffu);
    a1 += sn * b2f(sv.x >> 16);
    a2 += sn * b2f(sv.y & 0xffffu);
    a3 += sn * b2f(sv.y >> 16);

    int f0 = c * 4;
    float r0 = (f0 + 0 < FOUT) ? fmaxf(a0 + bias[f0 + 0], 0.f) : 0.f;
    float r1 = (f0 + 1 < FOUT) ? fmaxf(a1 + bias[f0 + 1], 0.f) : 0.f;
    float r2 = (f0 + 2 < FOUT) ? fmaxf(a2 + bias[f0 + 2], 0.f) : 0.f;
    float r3 = (f0 + 3 < FOUT) ? fmaxf(a3 + bias[f0 + 3], 0.f) : 0.f;

    uint2 o;
    o.x = (uint_t)f2b(r0) | ((uint_t)f2b(r1) << 16);
    o.y = (uint_t)f2b(r2) | ((uint_t)f2b(r3) << 16);
    ((uint2*)H)[(size_t)n * NC + c] = o;
}

// ---------------- mean-pool per graph + final linear + softmax ----------------
__global__ __launch_bounds__(256) void gcn_pool(
    const ushort_t* __restrict__ H, const int* __restrict__ batch,
    const float* __restrict__ Wf, const float* __restrict__ bf_,
    float* __restrict__ out, int N)
{
    __shared__ float pool[32];
    int g = blockIdx.x;
    int t = threadIdx.x;

    int lo = 0, hi = N;
    while (lo < hi) { int mid = (lo + hi) >> 1; if (batch[mid] < g) lo = mid + 1; else hi = mid; }
    int start = lo;
    lo = 0; hi = N;
    while (lo < hi) { int mid = (lo + hi) >> 1; if (batch[mid] < g + 1) lo = mid + 1; else hi = mid; }
    int end = lo;

    float acc[32];
    #pragma unroll
    for (int f = 0; f < 32; f++) acc[f] = 0.0f;
    for (int i = start + t; i < end; i += 256) {
        const uint2* hr = (const uint2*)H + (size_t)i * 8;
        #pragma unroll
        for (int q = 0; q < 8; q++) {
            uint2 v = hr[q];
            acc[4 * q + 0] += b2f(v.x & 0xffffu);
            acc[4 * q + 1] += b2f(v.x >> 16);
            acc[4 * q + 2] += b2f(v.y & 0xffffu);
            acc[4 * q + 3] += b2f(v.y >> 16);
        }
    }
    #pragma unroll
    for (int f = 0; f < 32; f++) {
        float v = acc[f];
        v += __shfl_down(v, 32, 64);
        v += __shfl_down(v, 16, 64);
        v += __shfl_down(v, 8, 64);
        v += __shfl_down(v, 4, 64);
        v += __shfl_down(v, 2, 64);
        v += __shfl_down(v, 1, 64);
        acc[f] = v;
    }
    if (t < 32) pool[t] = 0.0f;
    __syncthreads();
    if ((t & 63) == 0) {
        #pragma unroll
        for (int f = 0; f < 30; f++) atomicAdd(&pool[f], acc[f]);
    }
    __syncthreads();
    if (t == 0) {
        float inv = 1.0f / fmaxf((float)(end - start), 1.0f);
        float lg[10];
        #pragma unroll
        for (int j = 0; j < 10; j++) lg[j] = bf_[j];
        for (int f = 0; f < 30; f++) {
            float p = pool[f] * inv;
            #pragma unroll
            for (int j = 0; j < 10; j++) lg[j] += p * Wf[f * 10 + j];
        }
        float m = lg[0];
        #pragma unroll
        for (int j = 1; j < 10; j++) m = fmaxf(m, lg[j]);
        float s = 0.f;
        #pragma unroll
        for (int j = 0; j < 10; j++) { lg[j] = __expf(lg[j] - m); s += lg[j]; }
        float is = 1.0f / s;
        #pragma unroll
        for (int j = 0; j < 10; j++) out[g * 10 + j] = lg[j] * is;
    }
}

extern "C" void kernel_launch(void* const* d_in, const int* in_sizes, int n_in,
                              void* d_out, int out_size, void* d_ws, size_t ws_size,
                              hipStream_t stream) {
    (void)n_in; (void)out_size; (void)ws_size;
    const float* x   = (const float*)d_in[0];
    const int*   ei  = (const int*)d_in[1];
    const float* ew  = (const float*)d_in[2];
    const int*   bat = (const int*)d_in[3];
    const float* W1  = (const float*)d_in[4];
    const float* b1  = (const float*)d_in[5];
    const float* W2  = (const float*)d_in[6];
    const float* b2  = (const float*)d_in[7];
    const float* W3  = (const float*)d_in[8];
    const float* b3  = (const float*)d_in[9];
    const float* Wf  = (const float*)d_in[10];
    const float* bf_ = (const float*)d_in[11];
    float* out = (float*)d_out;

    const int N = in_sizes[3];       // 100000
    const int E = in_sizes[2];       // 3200000
    const int NB = (N + NPB - 1) / NPB;   // 782

    char* wsb = (char*)d_ws;
    size_t o = 0;
    auto take = [&](size_t bytes) -> char* {
        char* p = wsb + o;
        o += (bytes + 255) & ~(size_t)255;
        return p;
    };
    int*      bkt_cnt    = (int*)take(NBMAX * 4);             // zeroed each call
    int*      bkt_base   = (int*)take((NBMAX + 1) * 4);
    int*      bkt_cursor = (int*)take(NBMAX * 4);
    int*      rp         = (int*)take((size_t)(N + 1) * 4);
    float*    dis        = (float*)take((size_t)N * 4);
    uint2*    stage      = (uint2*)take((size_t)E * 8);       // dead after bsort; xw aliases it
    uint2*    edges      = (uint2*)take((size_t)E * 8);
    ushort_t* h          = (ushort_t*)take((size_t)N * 96 * 2);
    ushort_t* Wt1        = (ushort_t*)take(96 * 128 * 2);
    ushort_t* Wt2        = (ushort_t*)take(96 * 96 * 2);
    ushort_t* Wt3        = (ushort_t*)take(32 * 96 * 2);
    ushort_t* xw         = (ushort_t*)stage;                  // alias (E*8 >= N*96*2)

    const int gB = (E + 32767) / 32768;       // 98
    const int gM = (N + 63) / 64;

    hipMemsetAsync(bkt_cnt, 0, NBMAX * 4, stream);

    // CSR build: bucket hist -> scan -> scatter -> per-bucket sort -> norms
    gcn_bhist<<<gB, 1024, 0, stream>>>(ei, bkt_cnt, E, NB);
    gcn_wt<<<48, 256, 0, stream>>>(W1, W2, W3, Wt1, Wt2, Wt3);
    gcn_bscan<<<1, 256, 0, stream>>>(bkt_cnt, bkt_base, bkt_cursor, rp, NB, N, E);
    gcn_bscatter<<<gB, 1024, 0, stream>>>(ei, ew, bkt_cursor, stage, E, NB);
    gcn_bsort<<<NB, 256, 0, stream>>>(stage, edges, bkt_base, rp, dis, N);
    gcn_bnorm<<<NB, 256, 0, stream>>>(edges, bkt_base, dis, N);

    // layer 1: x[.,128](fp32) -> xw[.,96](bf16) -> h[.,96](bf16)
    gcn_gemm_mfma<128, 96, 96, 96, true><<<gM, 256, 0, stream>>>(x, Wt1, xw, N);
    gcn_agg<96, 96, 24, 192><<<(N + 7) / 8, 192, 0, stream>>>(xw, rp, edges, dis, b1, h, N);

    // layer 2
    gcn_gemm_mfma<96, 96, 96, 96, false><<<gM, 256, 0, stream>>>(h, Wt2, xw, N);
    gcn_agg<96, 96, 24, 192><<<(N + 7) / 8, 192, 0, stream>>>(xw, rp, edges, dis, b2, h, N);

    // layer 3 (FOUT=30 padded to 32)
    gcn_gemm_mfma<96, 30, 32, 32, false><<<gM, 256, 0, stream>>>(h, Wt3, xw, N);
    gcn_agg<30, 32, 8, 256><<<(N + 31) / 32, 256, 0, stream>>>(xw, rp, edges, dis, b3, h, N);

    // mean pool + classifier + softmax
    gcn_pool<<<256, 256, 0, stream>>>(h, bat, Wf, bf_, out, N);
}

// Round 6
// 634.420 us; speedup vs baseline: 2.0539x; 1.0934x over previous
//
#include <hip/hip_runtime.h>
#include <hip/hip_bf16.h>

typedef unsigned short ushort_t;
typedef unsigned int uint_t;
typedef unsigned long long u64_t;

typedef __attribute__((ext_vector_type(8))) short bf16x8;   // 8 bf16 (4 VGPRs)
typedef __attribute__((ext_vector_type(4))) float floatx4;  // MFMA C/D

#define DI __device__ __forceinline__

// NOTE: record packing uses 17 bits for src -> requires N < 131072. (N=100000)
#define NPB 128          // nodes per bucket
#define NBMAX 1024       // max buckets (N <= 131072)
#define CH 8             // src chunks (src>>14 -> 0..7); slice = 16384*192B = 3.1 MB

// bf16 bits -> f32
DI float b2f(uint_t lo16) {
    union { uint_t u; float f; } v; v.u = lo16 << 16; return v.f;
}
// f32 -> bf16 bits, round-to-nearest-even
DI ushort_t f2b(float f) {
    union { float f; uint_t u; } v; v.f = f;
    uint_t u = v.u;
    uint_t r = (u + 0x7fffu + ((u >> 16) & 1u)) >> 16;
    return (ushort_t)r;
}

// fma 8 bf16 feats (packed in uint4) into acc[8]
DI void fma8(float* a, uint4 v, float nm) {
    a[0] += nm * b2f(v.x & 0xffffu); a[1] += nm * b2f(v.x >> 16);
    a[2] += nm * b2f(v.y & 0xffffu); a[3] += nm * b2f(v.y >> 16);
    a[4] += nm * b2f(v.z & 0xffffu); a[5] += nm * b2f(v.z >> 16);
    a[6] += nm * b2f(v.w & 0xffffu); a[7] += nm * b2f(v.w >> 16);
}

// ---------------- P1: bucket histogram (LDS-binned) --------------------------
__global__ __launch_bounds__(1024) void gcn_bhist(
    const int* __restrict__ ei, int* __restrict__ bkt_cnt, int E, int NB)
{
    __shared__ int hist[NBMAX];
    int t = threadIdx.x;
    for (int b = t; b < NB; b += 1024) hist[b] = 0;
    __syncthreads();
    int base = blockIdx.x * 32768;
    int lim = min(32768, E - base);
    for (int i = t; i < lim; i += 1024) {
        int d = ei[(size_t)E + base + i];
        atomicAdd(&hist[d >> 7], 1);
    }
    __syncthreads();
    for (int b = t; b < NB; b += 1024) {
        int c = hist[b];
        if (c) atomicAdd(&bkt_cnt[b], c);
    }
}

// ---------------- P2: scan bucket counts -> bases/cursors --------------------
__global__ __launch_bounds__(256) void gcn_bscan(
    const int* __restrict__ bkt_cnt, int* __restrict__ bkt_base,
    int* __restrict__ bkt_cursor, int* __restrict__ rp, int NB, int N, int E)
{
    __shared__ int lds[256];
    int t = threadIdx.x;
    int v[4]; int s = 0;
    #pragma unroll
    for (int j = 0; j < 4; j++) {
        int b = t * 4 + j;
        v[j] = (b < NB) ? bkt_cnt[b] : 0;
        s += v[j];
    }
    lds[t] = s;
    __syncthreads();
    #pragma unroll
    for (int off = 1; off < 256; off <<= 1) {
        int y = (t >= off) ? lds[t - off] : 0;
        __syncthreads();
        lds[t] += y;
        __syncthreads();
    }
    int run = lds[t] - s;
    #pragma unroll
    for (int j = 0; j < 4; j++) {
        int b = t * 4 + j;
        if (b < NB) { bkt_base[b] = run; bkt_cursor[b] = run; }
        run += v[j];
    }
    if (t == 255) { bkt_base[NB] = E; rp[N] = E; }
}

// ---------------- P3: scatter records into bucket regions --------------------
// record: x = src | (dst&127)<<17 ; y = |w| (f32 bits). Per-edge atomics are LDS.
__global__ __launch_bounds__(1024) void gcn_bscatter(
    const int* __restrict__ ei, const float* __restrict__ ew,
    int* __restrict__ bkt_cursor, uint2* __restrict__ stage, int E, int NB)
{
    __shared__ int hist[NBMAX];
    __shared__ int cur[NBMAX];
    int t = threadIdx.x;
    for (int b = t; b < NB; b += 1024) hist[b] = 0;
    __syncthreads();
    int base = blockIdx.x * 32768;
    int lim = min(32768, E - base);
    for (int i = t; i < lim; i += 1024) {
        int d = ei[(size_t)E + base + i];
        atomicAdd(&hist[d >> 7], 1);
    }
    __syncthreads();
    for (int b = t; b < NB; b += 1024) {
        int c = hist[b];
        cur[b] = c ? atomicAdd(&bkt_cursor[b], c) : 0;
    }
    __syncthreads();
    for (int i = t; i < lim; i += 1024) {
        int e = base + i;
        int s = ei[e];
        int d = ei[(size_t)E + e];
        float w = fabsf(ew[e]);
        int pos = atomicAdd(&cur[d >> 7], 1);
        uint2 rec;
        rec.x = (uint_t)s | ((uint_t)(d & 127) << 17);
        rec.y = __float_as_uint(w);
        stage[pos] = rec;
    }
}

// ---------------- P4: per-bucket counting sort by (node, src-chunk) ----------
// key = dst_local*CH + (src>>14): edges land node-major, src-chunk-minor.
__global__ __launch_bounds__(256) void gcn_bsort(
    const uint2* __restrict__ stage, uint2* __restrict__ edges,
    const int* __restrict__ bkt_base, int* __restrict__ rp,
    float* __restrict__ dis, int N)
{
    int b = blockIdx.x;
    int base = bkt_base[b], end = bkt_base[b + 1];
    int cnte = end - base;
    int n0 = b << 7;
    __shared__ int cnt[NPB * CH];     // 1024 bins
    __shared__ float wsum[NPB];
    __shared__ int scn[256];
    __shared__ int cur[NPB * CH];
    int t = threadIdx.x;
    for (int i = t; i < NPB * CH; i += 256) cnt[i] = 0;
    if (t < NPB) wsum[t] = 0.0f;
    __syncthreads();
    for (int i = t; i < cnte; i += 256) {
        uint2 r = stage[base + i];
        int dl = (r.x >> 17) & 127;
        int ch = (r.x & 0x1FFFF) >> 14;
        atomicAdd(&cnt[dl * CH + ch], 1);
        atomicAdd(&wsum[dl], __uint_as_float(r.y));
    }
    __syncthreads();
    // scan the 1024 bins: thread t owns bins [4t, 4t+4)
    int v0 = cnt[t * 4], v1 = cnt[t * 4 + 1], v2 = cnt[t * 4 + 2], v3 = cnt[t * 4 + 3];
    int s = v0 + v1 + v2 + v3;
    scn[t] = s;
    __syncthreads();
    #pragma unroll
    for (int off = 1; off < 256; off <<= 1) {
        int y = (t >= off) ? scn[t - off] : 0;
        __syncthreads();
        scn[t] += y;
        __syncthreads();
    }
    int e0 = scn[t] - s;              // exclusive prefix of bin 4t
    int e1 = e0 + v0, e2 = e1 + v1, e3 = e2 + v2;
    cur[t * 4]     = base + e0;
    cur[t * 4 + 1] = base + e1;
    cur[t * 4 + 2] = base + e2;
    cur[t * 4 + 3] = base + e3;
    // node dl's start = prefix of bin dl*CH (CH=8 -> bin 8dl, owned by thread 2dl)
    if ((t & 1) == 0) {
        int dl = t >> 1;
        int n = n0 + dl;
        if (n < N) {
            rp[n] = base + e0;
            dis[n] = rsqrtf(wsum[dl] + 1.0f);
        }
    }
    __syncthreads();
    for (int i = t; i < cnte; i += 256) {
        uint2 r = stage[base + i];
        int dl = (r.x >> 17) & 127;
        int ch = (r.x & 0x1FFFF) >> 14;
        int pos = atomicAdd(&cur[dl * CH + ch], 1);
        edges[pos] = r;
    }
}

// ---------------- P5: rewrite w -> nrm = dis[src]*|w|*dis[dst] ---------------
__global__ __launch_bounds__(256) void gcn_bnorm(
    uint2* __restrict__ edges, const int* __restrict__ bkt_base,
    const float* __restrict__ dis, int N)
{
    int b = blockIdx.x;
    int base = bkt_base[b], end = bkt_base[b + 1];
    int n0 = b << 7;
    __shared__ float ldis[NPB];
    int t = threadIdx.x;
    if (t < NPB) { int n = n0 + t; ldis[t] = (n < N) ? dis[n] : 0.0f; }
    __syncthreads();
    for (int i = t; i < end - base; i += 256) {
        uint2 r = edges[base + i];
        int s = r.x & 0x1FFFF;
        float w = __uint_as_float(r.y);
        float nm = dis[s] * w * ldis[(r.x >> 17) & 127];
        r.y = __float_as_uint(nm);
        edges[base + i] = r;
    }
}

// ---------------- weight transpose + bf16 convert (once per call, tiny) -------
__global__ __launch_bounds__(256) void gcn_wt(
    const float* __restrict__ W1, const float* __restrict__ W2,
    const float* __restrict__ W3,
    ushort_t* __restrict__ Wt1, ushort_t* __restrict__ Wt2,
    ushort_t* __restrict__ Wt3)
{
    int i = blockIdx.x * 256 + threadIdx.x;
    if (i < 96 * 128) {                       // layer 1: Wt1[96][128]
        int n = i / 128, k = i % 128;
        Wt1[i] = f2b(W1[k * 96 + n]);
    }
    if (i < 96 * 96) {                        // layer 2: Wt2[96][96]
        int n = i / 96, k = i % 96;
        Wt2[i] = f2b(W2[k * 96 + n]);
    }
    if (i < 32 * 96) {                        // layer 3: Wt3[32][96], pad rows 30,31
        int n = i / 96, k = i % 96;
        Wt3[i] = f2b((n < 30) ? W3[k * 30 + n] : 0.0f);
    }
}

// ---------------- MFMA GEMM: Y[64-row tile, FOUTP] = X @ W ---------------------
template<int K, int FOUT, int NTR, int FOUTP, bool XF32>
__global__ __launch_bounds__(256) void gcn_gemm_mfma(
    const void* __restrict__ Xv, const ushort_t* __restrict__ Wt,
    ushort_t* __restrict__ Y, int N)
{
    constexpr int KS = K + 8;
    constexpr int KT = K / 32;
    constexpr int NT = NTR / 16;
    __shared__ ushort_t xs[64 * KS];
    __shared__ ushort_t ws[NTR * KS];

    int t = threadIdx.x;
    int mbase = blockIdx.x * 64;

    {
        constexpr int TOT = NTR * (K / 8);
        const uint4* wg = (const uint4*)Wt;
        for (int i = t; i < TOT; i += 256) {
            int r = i / (K / 8), c8 = i % (K / 8);
            *(uint4*)(ws + r * KS + c8 * 8) = wg[i];
        }
    }
    if (XF32) {
        const float* X = (const float*)Xv;
        constexpr int TOT = 64 * (K / 4);
        for (int i = t; i < TOT; i += 256) {
            int row = i / (K / 4), c4 = i % (K / 4);
            int rg = mbase + row; if (rg >= N) rg = N - 1;
            float4 v = *(const float4*)(X + (size_t)rg * K + c4 * 4);
            uint2 pv;
            pv.x = (uint_t)f2b(v.x) | ((uint_t)f2b(v.y) << 16);
            pv.y = (uint_t)f2b(v.z) | ((uint_t)f2b(v.w) << 16);
            *(uint2*)(xs + row * KS + c4 * 4) = pv;
        }
    } else {
        const ushort_t* X = (const ushort_t*)Xv;
        constexpr int TOT = 64 * (K / 8);
        for (int i = t; i < TOT; i += 256) {
            int row = i / (K / 8), c8 = i % (K / 8);
            int rg = mbase + row; if (rg >= N) rg = N - 1;
            *(uint4*)(xs + row * KS + c8 * 8) = *(const uint4*)(X + (size_t)rg * K + c8 * 8);
        }
    }
    __syncthreads();

    int wave = t >> 6;
    int lane = t & 63;
    int l15 = lane & 15, quad = lane >> 4;

    bf16x8 af[KT];
    #pragma unroll
    for (int kt = 0; kt < KT; kt++)
        af[kt] = *(const bf16x8*)(xs + (wave * 16 + l15) * KS + kt * 32 + quad * 8);

    floatx4 acc[NT];
    #pragma unroll
    for (int nt = 0; nt < NT; nt++) acc[nt] = (floatx4){0.f, 0.f, 0.f, 0.f};

    #pragma unroll
    for (int nt = 0; nt < NT; nt++) {
        #pragma unroll
        for (int kt = 0; kt < KT; kt++) {
            bf16x8 bfr = *(const bf16x8*)(ws + (nt * 16 + l15) * KS + kt * 32 + quad * 8);
            acc[nt] = __builtin_amdgcn_mfma_f32_16x16x32_bf16(af[kt], bfr, acc[nt], 0, 0, 0);
        }
    }

    #pragma unroll
    for (int nt = 0; nt < NT; nt++) {
        int col = nt * 16 + l15;
        #pragma unroll
        for (int r = 0; r < 4; r++) {
            int row = mbase + wave * 16 + quad * 4 + r;
            if (row < N) {
                float v = (col < FOUT) ? acc[nt][r] : 0.0f;
                Y[(size_t)row * FOUTP + col] = f2b(v);
            }
        }
    }
}

// ---------------- aggregation: H[n] = relu(b + dis[n]^2*XW[n] + sum_e nrm*XW[src]) ----
// LPN lanes per node; each lane owns 8 bf16 feats (one uint4). Edge loop
// unrolled x4: 4 independent record+gather chains in flight (MLP).
template<int FOUT, int FOUTP, int LPN, int BLK>
__global__ __launch_bounds__(BLK) void gcn_agg(
    const ushort_t* __restrict__ XW, const int* __restrict__ rp,
    const uint2* __restrict__ edges,
    const float* __restrict__ dis, const float* __restrict__ bias,
    ushort_t* __restrict__ H, int N)
{
    constexpr int NC = FOUTP / 8;           // uint4 per row
    int n = blockIdx.x * (BLK / LPN) + threadIdx.x / LPN;
    int c = threadIdx.x % LPN;
    if (n >= N) return;
    const uint4* xwc = (const uint4*)XW;
    const u64_t* ed64 = (const u64_t*)edges;

    int beg = rp[n], end = rp[n + 1];
    float a[8];
    #pragma unroll
    for (int j = 0; j < 8; j++) a[j] = 0.0f;

    int e = beg;
    for (; e + 4 <= end; e += 4) {
        u64_t r0 = __builtin_nontemporal_load(ed64 + e);
        u64_t r1 = __builtin_nontemporal_load(ed64 + e + 1);
        u64_t r2 = __builtin_nontemporal_load(ed64 + e + 2);
        u64_t r3 = __builtin_nontemporal_load(ed64 + e + 3);
        uint4 v0 = xwc[(size_t)((uint_t)r0 & 0x1FFFF) * NC + c];
        uint4 v1 = xwc[(size_t)((uint_t)r1 & 0x1FFFF) * NC + c];
        uint4 v2 = xwc[(size_t)((uint_t)r2 & 0x1FFFF) * NC + c];
        uint4 v3 = xwc[(size_t)((uint_t)r3 & 0x1FFFF) * NC + c];
        fma8(a, v0, __uint_as_float((uint_t)(r0 >> 32)));
        fma8(a, v1, __uint_as_float((uint_t)(r1 >> 32)));
        fma8(a, v2, __uint_as_float((uint_t)(r2 >> 32)));
        fma8(a, v3, __uint_as_float((uint_t)(r3 >> 32)));
    }
    for (; e < end; e++) {
        u64_t r0 = __builtin_nontemporal_load(ed64 + e);
        uint4 v0 = xwc[(size_t)((uint_t)r0 & 0x1FFFF) * NC + c];
        fma8(a, v0, __uint_as_float((uint_t)(r0 >> 32)));
    }
    float d = dis[n];
    float sn = d * d;
    uint4 sv = xwc[(size_t)n * NC + c];
    fma8(a, sv, sn);

    int f0 = c * 8;
    uint_t o[4];
    #pragma unroll
    for (int p = 0; p < 4; p++) {
        float rA = (f0 + 2 * p     < FOUT) ? fmaxf(a[2 * p]     + bias[f0 + 2 * p],     0.f) : 0.f;
        float rB = (f0 + 2 * p + 1 < FOUT) ? fmaxf(a[2 * p + 1] + bias[f0 + 2 * p + 1], 0.f) : 0.f;
        o[p] = (uint_t)f2b(rA) | ((uint_t)f2b(rB) << 16);
    }
    uint4 ov = {o[0], o[1], o[2], o[3]};
    *((uint4*)H + (size_t)n * NC + c) = ov;
}

// ---------------- mean-pool per graph + final linear + softmax ----------------
__global__ __launch_bounds__(256) void gcn_pool(
    const ushort_t* __restrict__ H, const int* __restrict__ batch,
    const float* __restrict__ Wf, const float* __restrict__ bf_,
    float* __restrict__ out, int N)
{
    __shared__ float pool[32];
    int g = blockIdx.x;
    int t = threadIdx.x;

    int lo = 0, hi = N;
    while (lo < hi) { int mid = (lo + hi) >> 1; if (batch[mid] < g) lo = mid + 1; else hi = mid; }
    int start = lo;
    lo = 0; hi = N;
    while (lo < hi) { int mid = (lo + hi) >> 1; if (batch[mid] < g + 1) lo = mid + 1; else hi = mid; }
    int end = lo;

    float acc[32];
    #pragma unroll
    for (int f = 0; f < 32; f++) acc[f] = 0.0f;
    for (int i = start + t; i < end; i += 256) {
        const uint2* hr = (const uint2*)H + (size_t)i * 8;
        #pragma unroll
        for (int q = 0; q < 8; q++) {
            uint2 v = hr[q];
            acc[4 * q + 0] += b2f(v.x & 0xffffu);
            acc[4 * q + 1] += b2f(v.x >> 16);
            acc[4 * q + 2] += b2f(v.y & 0xffffu);
            acc[4 * q + 3] += b2f(v.y >> 16);
        }
    }
    #pragma unroll
    for (int f = 0; f < 32; f++) {
        float v = acc[f];
        v += __shfl_down(v, 32, 64);
        v += __shfl_down(v, 16, 64);
        v += __shfl_down(v, 8, 64);
        v += __shfl_down(v, 4, 64);
        v += __shfl_down(v, 2, 64);
        v += __shfl_down(v, 1, 64);
        acc[f] = v;
    }
    if (t < 32) pool[t] = 0.0f;
    __syncthreads();
    if ((t & 63) == 0) {
        #pragma unroll
        for (int f = 0; f < 30; f++) atomicAdd(&pool[f], acc[f]);
    }
    __syncthreads();
    if (t == 0) {
        float inv = 1.0f / fmaxf((float)(end - start), 1.0f);
        float lg[10];
        #pragma unroll
        for (int j = 0; j < 10; j++) lg[j] = bf_[j];
        for (int f = 0; f < 30; f++) {
            float p = pool[f] * inv;
            #pragma unroll
            for (int j = 0; j < 10; j++) lg[j] += p * Wf[f * 10 + j];
        }
        float m = lg[0];
        #pragma unroll
        for (int j = 1; j < 10; j++) m = fmaxf(m, lg[j]);
        float s = 0.f;
        #pragma unroll
        for (int j = 0; j < 10; j++) { lg[j] = __expf(lg[j] - m); s += lg[j]; }
        float is = 1.0f / s;
        #pragma unroll
        for (int j = 0; j < 10; j++) out[g * 10 + j] = lg[j] * is;
    }
}

extern "C" void kernel_launch(void* const* d_in, const int* in_sizes, int n_in,
                              void* d_out, int out_size, void* d_ws, size_t ws_size,
                              hipStream_t stream) {
    (void)n_in; (void)out_size; (void)ws_size;
    const float* x   = (const float*)d_in[0];
    const int*   ei  = (const int*)d_in[1];
    const float* ew  = (const float*)d_in[2];
    const int*   bat = (const int*)d_in[3];
    const float* W1  = (const float*)d_in[4];
    const float* b1  = (const float*)d_in[5];
    const float* W2  = (const float*)d_in[6];
    const float* b2  = (const float*)d_in[7];
    const float* W3  = (const float*)d_in[8];
    const float* b3  = (const float*)d_in[9];
    const float* Wf  = (const float*)d_in[10];
    const float* bf_ = (const float*)d_in[11];
    float* out = (float*)d_out;

    const int N = in_sizes[3];       // 100000
    const int E = in_sizes[2];       // 3200000
    const int NB = (N + NPB - 1) / NPB;   // 782

    char* wsb = (char*)d_ws;
    size_t o = 0;
    auto take = [&](size_t bytes) -> char* {
        char* p = wsb + o;
        o += (bytes + 255) & ~(size_t)255;
        return p;
    };
    int*      bkt_cnt    = (int*)take(NBMAX * 4);             // zeroed each call
    int*      bkt_base   = (int*)take((NBMAX + 1) * 4);
    int*      bkt_cursor = (int*)take(NBMAX * 4);
    int*      rp         = (int*)take((size_t)(N + 1) * 4);
    float*    dis        = (float*)take((size_t)N * 4);
    uint2*    stage      = (uint2*)take((size_t)E * 8);       // dead after bsort; xw aliases it
    uint2*    edges      = (uint2*)take((size_t)E * 8);
    ushort_t* h          = (ushort_t*)take((size_t)N * 96 * 2);
    ushort_t* Wt1        = (ushort_t*)take(96 * 128 * 2);
    ushort_t* Wt2        = (ushort_t*)take(96 * 96 * 2);
    ushort_t* Wt3        = (ushort_t*)take(32 * 96 * 2);
    ushort_t* xw         = (ushort_t*)stage;                  // alias (E*8 >= N*96*2)

    const int gB = (E + 32767) / 32768;       // 98
    const int gM = (N + 63) / 64;

    hipMemsetAsync(bkt_cnt, 0, NBMAX * 4, stream);

    // CSR build: bucket hist -> scan -> scatter -> per-bucket sort -> norms
    gcn_bhist<<<gB, 1024, 0, stream>>>(ei, bkt_cnt, E, NB);
    gcn_wt<<<48, 256, 0, stream>>>(W1, W2, W3, Wt1, Wt2, Wt3);
    gcn_bscan<<<1, 256, 0, stream>>>(bkt_cnt, bkt_base, bkt_cursor, rp, NB, N, E);
    gcn_bscatter<<<gB, 1024, 0, stream>>>(ei, ew, bkt_cursor, stage, E, NB);
    gcn_bsort<<<NB, 256, 0, stream>>>(stage, edges, bkt_base, rp, dis, N);
    gcn_bnorm<<<NB, 256, 0, stream>>>(edges, bkt_base, dis, N);

    // layer 1: x[.,128](fp32) -> xw[.,96](bf16) -> h[.,96](bf16)
    gcn_gemm_mfma<128, 96, 96, 96, true><<<gM, 256, 0, stream>>>(x, Wt1, xw, N);
    gcn_agg<96, 96, 12, 192><<<(N + 15) / 16, 192, 0, stream>>>(xw, rp, edges, dis, b1, h, N);

    // layer 2
    gcn_gemm_mfma<96, 96, 96, 96, false><<<gM, 256, 0, stream>>>(h, Wt2, xw, N);
    gcn_agg<96, 96, 12, 192><<<(N + 15) / 16, 192, 0, stream>>>(xw, rp, edges, dis, b2, h, N);

    // layer 3 (FOUT=30 padded to 32)
    gcn_gemm_mfma<96, 30, 32, 32, false><<<gM, 256, 0, stream>>>(h, Wt3, xw, N);
    gcn_agg<30, 32, 4, 256><<<(N + 63) / 64, 256, 0, stream>>>(xw, rp, edges, dis, b3, h, N);

    // mean pool + classifier + softmax
    gcn_pool<<<256, 256, 0, stream>>>(h, bat, Wf, bf_, out, N);
}